// Round 2
// baseline (80.002 us; speedup 1.0000x reference)
//
#include <hip/hip_runtime.h>

// CTC batch loss forward (Keras ctc_batch_cost semantics).
// B=2048, T=256, L=32, V=128, blank = V-1 = 127, S = 2L+1 = 65.
// One wave64 per batch item: lane s owns extended state s (0..63),
// lane 0 additionally owns state 64 (blank; shares lane 0's blank logp).
// Rows streamed into wave-private LDS via global_load_lds (dwordx4),
// double-buffered with counted vmcnt; per-state gather is an LDS read.

constexpr int Bb = 2048;
constexpr int Tt = 256;
constexpr int Ll = 32;
constexpr int Vv = 128;
constexpr int BLANK = Vv - 1;
constexpr int CH = 16;            // rows per chunk (16 rows * 512 B = 8 KB)
constexpr int NC = Tt / CH;       // 16 chunks
#define EPSF 1e-7f
#define NEGF -1e30f

#define GLOBAL_AS(p) ((const __attribute__((address_space(1))) void*)(p))
#define LDS_AS(p)    ((__attribute__((address_space(3))) void*)(p))

__global__ __launch_bounds__(256) void ctc_fwd(const int* __restrict__ y_true,
                                               const float* __restrict__ y_pred,
                                               float* __restrict__ out) {
    const int wv   = threadIdx.x >> 6;        // wave id within block (0..3)
    const int lane = threadIdx.x & 63;
    const int w    = blockIdx.x * 4 + wv;     // batch item

    // 4 waves x 2 buffers x (16 rows * 128 floats) = 64 KB / block
    __shared__ float lds[4][2][CH * Vv];

    // --- extended-label symbol for this lane's state ---
    int sym = BLANK;
    if (lane & 1) sym = y_true[w * Ll + (lane >> 1)];
    const int sym2 = __shfl_up(sym, 2);
    const bool skip = (lane & 1) && (lane >= 3) && (sym != sym2);

    const float* gbase = y_pred + (size_t)w * Tt * Vv;

    // stage one 16-row chunk (8 KB) into LDS: 8 x dwordx4, perfectly coalesced
    auto stage = [&](float* l, int c) {
        const float* g = gbase + (size_t)c * (CH * Vv) + lane * 4;
#pragma unroll
        for (int i = 0; i < 8; ++i)
            __builtin_amdgcn_global_load_lds(GLOBAL_AS(g + i * 256),
                                             LDS_AS(l + i * 256), 16, 0, 0);
    };

    float a   = NEGF;   // alpha[lane]
    float a64 = NEGF;   // alpha[64] (meaningful on lane 0)

    // --- one DP step given raw prob p = y_pred[b][t][sym] ---
    auto step = [&](float p) {
        const float lp  = __logf(p + EPSF);
        const float up1 = __shfl_up(a, 1);
        const float up2 = __shfl_up(a, 2);
        const float a63 = __uint_as_float(
            __builtin_amdgcn_readlane(__float_as_uint(a), 63));
        const float m1 = (lane >= 1) ? up1 : NEGF;
        const float m2 = skip ? up2 : NEGF;
        // 3-way logaddexp for states 0..63
        const float hi = fmaxf(a, fmaxf(m1, m2));
        const float sm = __expf(a - hi) + __expf(m1 - hi) + __expf(m2 - hi);
        const float na = hi + __logf(sm) + lp;
        // state 64 (blank): logaddexp(alpha[64], alpha[63]) + lp_blank
        const float hi2 = fmaxf(a64, a63);
        const float sm2 = __expf(a64 - hi2) + __expf(a63 - hi2);
        a64 = hi2 + __logf(sm2) + lp;
        a   = na;
    };

    // --- prologue: two chunks in flight ---
    stage(&lds[wv][0][0], 0);
    stage(&lds[wv][1][0], 1);

    for (int c = 0; c < NC; ++c) {
        // wait for chunk c only (chunk c+1 stays in flight) — counted vmcnt
        if (c + 1 < NC) asm volatile("s_waitcnt vmcnt(8)" ::: "memory");
        else            asm volatile("s_waitcnt vmcnt(0)" ::: "memory");
        float* cur = &lds[wv][c & 1][0];
        if (c == 0) {
            // t = 0 init: only states 0 and 1 reachable
            const float lp0 = __logf(cur[sym] + EPSF);
            a = (lane <= 1) ? lp0 : NEGF;
#pragma unroll
            for (int i = 1; i < CH; ++i) step(cur[i * Vv + sym]);
        } else {
#pragma unroll
            for (int i = 0; i < CH; ++i) step(cur[i * Vv + sym]);
        }
        // all ds_reads of `cur` retired before overwriting it
        asm volatile("s_waitcnt lgkmcnt(0)" ::: "memory");
        if (c + 2 < NC) stage(cur, c + 2);
    }

    // --- loss = -logaddexp(alpha[S-1]=a64, alpha[S-2]=alpha[63]) ---
    const float a63 = __uint_as_float(
        __builtin_amdgcn_readlane(__float_as_uint(a), 63));
    if (lane == 0) {
        const float hi = fmaxf(a64, a63);
        const float r  = hi + __logf(__expf(a64 - hi) + __expf(a63 - hi));
        out[w] = -r;
    }
}

extern "C" void kernel_launch(void* const* d_in, const int* in_sizes, int n_in,
                              void* d_out, int out_size, void* d_ws, size_t ws_size,
                              hipStream_t stream) {
    const int*   y_true = (const int*)d_in[0];
    const float* y_pred = (const float*)d_in[1];
    float*       out    = (float*)d_out;
    ctc_fwd<<<dim3(Bb / 4), dim3(256), 0, stream>>>(y_true, y_pred, out);
}

// Round 4
// 50.475 us; speedup vs baseline: 1.5850x; 1.5850x over previous
//
#include <hip/hip_runtime.h>

// CTC batch loss forward (Keras ctc_batch_cost semantics).
// B=2048, T=256, L=32, V=128, blank=V-1=127, S=2L+1=65.
// One wave64 per batch item: lane s owns state s (0..63); lane 0 also owns
// state 64 (final blank, shares lane 0's blank log-prob).
// alpha kept in streaming-softmax form: alpha2 = m + log2(p)  (base-2).
// m-recurrence = shfl -> max3 -> add  (no transcendental on the chain);
// p folded into m every 8 steps. Direct global gather loads, PF=16 ring.

constexpr int Bb = 2048;
constexpr int Tt = 256;
constexpr int Ll = 32;
constexpr int Vv = 128;
constexpr int BLANK = Vv - 1;
constexpr int PF = 16;
#define EPSF 1e-7f
#define NEGF -1e30f
#define LN2F 0.6931471805599453f

__device__ __forceinline__ float fexp2(float x) { return __builtin_amdgcn_exp2f(x); }
__device__ __forceinline__ float flog2(float x) { return __builtin_amdgcn_logf(x); }

__device__ __forceinline__ float rdlane63(float v) {
    return __uint_as_float(__builtin_amdgcn_readlane(__float_as_uint(v), 63));
}

__global__ __launch_bounds__(256) void ctc_fwd(const int* __restrict__ y_true,
                                               const float* __restrict__ y_pred,
                                               float* __restrict__ out) {
    const int w    = blockIdx.x * 4 + (threadIdx.x >> 6);   // batch item
    const int lane = threadIdx.x & 63;

    // extended-label symbol for this lane's state
    int sym = BLANK;
    if (lane & 1) sym = y_true[w * Ll + (lane >> 1)];
    const int sym2 = __shfl_up(sym, 2);
    const bool skip = (lane & 1) && (lane >= 3) && (sym != sym2);

    const float* rp = y_pred + (size_t)w * Tt * Vv + sym;

    // t = 0 init: only states 0,1 reachable
    const float lp0 = flog2(rp[0] + EPSF);
    float m   = (lane <= 1) ? lp0 : NEGF;
    float p   = 1.0f;
    float m64 = NEGF, p64 = 1.0f;     // state 64 (meaningful on lane 0)

    auto step = [&](float prob) {
        const float lp2 = flog2(prob + EPSF);            // off-chain
        const float m1  = __shfl_up(m, 1);
        const float m2s = __shfl_up(m, 2);
        const float p1  = __shfl_up(p, 1);
        const float p2  = __shfl_up(p, 2);
        const float m63 = rdlane63(m);                   // pre-update
        const float p63 = rdlane63(p);
        const float m1g = (lane >= 1) ? m1 : NEGF;
        const float m2g = skip ? m2s : NEGF;
        // states 0..63
        const float hi  = fmaxf(fmaxf(m, m1g), m2g);     // -> v_max3
        const float pn  = p  * fexp2(m   - hi)
                        + p1 * fexp2(m1g - hi)
                        + p2 * fexp2(m2g - hi);          // dead terms weigh 0
        // state 64: from {64, 63}, lp is lane 0's blank lp2
        const float hi2  = fmaxf(m64, m63);
        const float pn64 = p64 * fexp2(m64 - hi2) + p63 * fexp2(m63 - hi2);
        m   = hi  + lp2;  p   = pn;
        m64 = hi2 + lp2;  p64 = pn64;
    };
    auto renorm = [&]() {   // p <= 3^8 between renorms, fp32-safe
        m   += flog2(fmaxf(p,   1e-30f));  p   = 1.0f;
        m64 += flog2(fmaxf(p64, 1e-30f));  p64 = 1.0f;
    };

    // software-pipelined gather ring over t = 1..255
    float buf[PF];
#pragma unroll
    for (int i = 0; i < PF; ++i) buf[i] = rp[(size_t)(1 + i) * Vv];

    for (int tb = 1; tb + PF <= Tt; tb += PF) {   // t = 1..240
#pragma unroll
        for (int i = 0; i < PF; ++i) {
            const float pr = buf[i];
            const int   tn = tb + i + PF;
            if (tn < Tt) buf[i] = rp[(size_t)tn * Vv];
            step(pr);
            if ((i & 7) == 7) renorm();
        }
    }
#pragma unroll
    for (int i = 0; i < PF - 1; ++i) {            // t = 241..255
        step(buf[i]);
        if (i == 7) renorm();
    }

    // loss = -ln2 * logaddexp2(alpha2[63], alpha2[64])
    const float a63 = rdlane63(m + flog2(fmaxf(p, 1e-30f)));
    if (lane == 0) {
        const float a64 = m64 + flog2(fmaxf(p64, 1e-30f));
        const float h = fmaxf(a63, a64);
        const float r = h + flog2(fexp2(a63 - h) + fexp2(a64 - h));
        out[w] = -r * LN2F;
    }
}

extern "C" void kernel_launch(void* const* d_in, const int* in_sizes, int n_in,
                              void* d_out, int out_size, void* d_ws, size_t ws_size,
                              hipStream_t stream) {
    const int*   y_true = (const int*)d_in[0];
    const float* y_pred = (const float*)d_in[1];
    float*       out    = (float*)d_out;
    ctc_fwd<<<dim3(Bb / 4), dim3(256), 0, stream>>>(y_true, y_pred, out);
}